// Round 9
// baseline (47.985 us; speedup 1.0000x reference)
//
#include <hip/hip_runtime.h>
#include <math.h>

#define NB       16
#define IMG      127
#define PLANE    (IMG * IMG)            // 16129
#define PN       4096
#define PPT      8                      // output rows per thread (K1/K3)
#define NROW     (2 * PPT + 1)          // 17 image rows per thread window

// ws layout (floats): [0 .. 1024*64)  per-bg Gram partials (54 used, stride 64)
//                     [WS_UC .. +1024*16)  per-bg u[9] + c (stride 16)
#define WS_UC    (1024 * 64)

// index into upper-triangular symmetric 9x9 storage, requires p<=q
__device__ __forceinline__ constexpr int symidx(int p, int q) {
    return p * 9 - (p * (p - 1)) / 2 + (q - p);
}

// lane i <- lane i-1 (wave-wide shift); lane 0 <- 0 (bound_ctrl) = left zero-pad
__device__ __forceinline__ float dpp_wave_shr1(float v) {
    return __builtin_bit_cast(float, __builtin_amdgcn_update_dpp(
        0, __builtin_bit_cast(int, v), 0x138, 0xf, 0xf, true));
}

// full 64-lane sum via 6 DPP adds (VALU only); result valid in lane 63
__device__ __forceinline__ float wave_reduce_full(float v) {
#define DPP_ADD(ctrl)                                                          \
    v += __builtin_bit_cast(float, __builtin_amdgcn_update_dpp(                \
             0, __builtin_bit_cast(int, v), (ctrl), 0xf, 0xf, true))
    DPP_ADD(0x111);   // row_shr:1
    DPP_ADD(0x112);   // row_shr:2
    DPP_ADD(0x114);   // row_shr:4
    DPP_ADD(0x118);   // row_shr:8
    DPP_ADD(0x142);   // row_bcast:15
    DPP_ADD(0x143);   // row_bcast:31 -> lane63 = sum(0..63)
#undef DPP_ADD
    return v;
}

// intra-wave cross-lane LDS exchange fence (r8-proven; r7 failed without it)
#define XLANE_FENCE() __builtin_amdgcn_wave_barrier()

// ---------------- K1: per-bg Gram partials -> ws ----------------
__global__ void __launch_bounds__(512, 2)
k1_gram(const float* __restrict__ x, float* __restrict__ wsp)
{
    __shared__ float red[8 * 54];

    const int bg  = blockIdx.x;
    const int tid = threadIdx.x;
    const int ow  = tid & 63;
    const int wv  = tid >> 6;
    const int oh0 = wv * PPT;

    const float* __restrict__ xp = x + (size_t)bg * PLANE;
    const bool c2  = (ow < 63);
    const int  ih0 = oh0 * 2 - 1;

    // 17-row global register window (r6-proven): 34 independent loads -> MLP
    float e0[NROW], e1[NROW];
    #pragma unroll
    for (int r = 0; r < NROW; ++r) {
        const int ih = ih0 + r;                 // wave-uniform
        float a = 0.f, b = 0.f;
        if ((unsigned)ih < (unsigned)IMG) {
            const float* __restrict__ rp = xp + ih * IMG + 2 * ow;
            a = rp[0];
            if (c2) b = rp[1];                  // exec-masked: lane 63 never reads
        }
        e0[r] = a; e1[r] = b;
    }

    // one-pass Gram (45) + column sums (9)
    float acc[45], mm[9];
    #pragma unroll
    for (int i = 0; i < 45; ++i) acc[i] = 0.f;
    #pragma unroll
    for (int i = 0; i < 9; ++i)  mm[i] = 0.f;

    #pragma unroll
    for (int k = 0; k < PPT; ++k) {
        float v[9];
        #pragma unroll
        for (int r = 0; r < 3; ++r) {
            const int rr = 2 * k + r;
            v[3 * r + 0] = dpp_wave_shr1(e1[rr]);   // col 2ow-1
            v[3 * r + 1] = e0[rr];                  // col 2ow
            v[3 * r + 2] = e1[rr];                  // col 2ow+1
        }
        int idx = 0;
        #pragma unroll
        for (int p = 0; p < 9; ++p) {
            mm[p] += v[p];
            #pragma unroll
            for (int q = p; q < 9; ++q)
                acc[idx++] += v[p] * v[q];
        }
    }

    #pragma unroll
    for (int i = 0; i < 45; ++i) acc[i] = wave_reduce_full(acc[i]);
    #pragma unroll
    for (int i = 0; i < 9; ++i)  mm[i] = wave_reduce_full(mm[i]);
    if (ow == 63) {
        #pragma unroll
        for (int i = 0; i < 45; ++i) red[wv * 54 + i]      = acc[i];
        #pragma unroll
        for (int i = 0; i < 9; ++i)  red[wv * 54 + 45 + i] = mm[i];
    }
    __syncthreads();

    if (tid < 54) {
        float s = 0.f;
        #pragma unroll
        for (int w = 0; w < 8; ++w) s += red[w * 54 + tid];
        wsp[bg * 64 + tid] = s;
    }
}

// ---------------- K2: tiny math per bg -> u[9], c ----------------
__global__ void __launch_bounds__(64, 4)
k2_tiny(const float* __restrict__ wsp, float* __restrict__ wuc,
        const float* __restrict__ Wq, const float* __restrict__ bq,
        const float* __restrict__ Wk, const float* __restrict__ bk,
        const float* __restrict__ Wv, const float* __restrict__ bv,
        const float* __restrict__ Wo, const float* __restrict__ bo)
{
    __shared__ float Msh[45], msh[9], MW[81], en[81], at[81], wt[9];

    const int bg   = blockIdx.x;
    const int g    = bg & 63;
    const int lane = threadIdx.x;               // 0..63, one wave

    const float* __restrict__ Wqg = Wq + g * 81;
    const float* __restrict__ Wkg = Wk + g * 81;
    const float* __restrict__ Wvg = Wv + g * 81;

    if (lane < 54) {                            // load per-bg Gram sums
        const float s = wsp[bg * 64 + lane];
        if (lane < 45) Msh[lane]      = s;
        else           msh[lane - 45] = s;
    }
    XLANE_FENCE();
    #pragma unroll
    for (int r = 0; r < 2; ++r) {               // MW = M @ Wq
        const int e = lane + r * 64;
        if (e < 81) {
            const int p = e / 9, t = e % 9;
            float a2 = 0.f;
            #pragma unroll
            for (int q = 0; q < 9; ++q) {
                const int a_ = p < q ? p : q, b_ = p < q ? q : p;
                a2 += Msh[symidx(a_, b_)] * Wqg[q * 9 + t];
            }
            MW[e] = a2;
        }
    }
    XLANE_FENCE();
    #pragma unroll
    for (int r = 0; r < 2; ++r) {               // energy
        const int e = lane + r * 64;
        if (e < 81) {
            const int s = e / 9, t = e % 9;
            float km = 0.f, qm = 0.f, a2 = 0.f;
            #pragma unroll
            for (int p = 0; p < 9; ++p) {
                km += Wkg[p * 9 + s] * msh[p];
                qm += Wqg[p * 9 + t] * msh[p];
                a2 += Wkg[p * 9 + s] * MW[p * 9 + t];
            }
            en[e] = a2 + (float)PN * bk[g * 9 + s] * bq[g * 9 + t]
                  + km * bq[g * 9 + t] + bk[g * 9 + s] * qm;
        }
    }
    XLANE_FENCE();
    if (lane < 9) {                             // softmax over t per row s
        const int s = lane;
        float mx = en[s * 9];
        #pragma unroll
        for (int t = 1; t < 9; ++t) mx = fmaxf(mx, en[s * 9 + t]);
        float ex[9], sum = 0.f;
        #pragma unroll
        for (int t = 0; t < 9; ++t) { ex[t] = expf(en[s * 9 + t] - mx); sum += ex[t]; }
        const float inv = 1.f / sum;
        #pragma unroll
        for (int t = 0; t < 9; ++t) at[s * 9 + t] = ex[t] * inv;
    }
    XLANE_FENCE();
    if (lane < 9) {                             // wt[t] = sum_s attn[s,t] * Wo[s]
        const int t = lane;
        float w = 0.f;
        #pragma unroll
        for (int s = 0; s < 9; ++s) w += at[s * 9 + t] * Wo[g * 9 + s];
        wt[t] = w;
    }
    XLANE_FENCE();
    if (lane < 9) {                             // u[p] = sum_t Wv[p,t] * wt[t]
        const int p = lane;
        float uu = 0.f;
        #pragma unroll
        for (int t = 0; t < 9; ++t) uu += Wvg[p * 9 + t] * wt[t];
        wuc[bg * 16 + p] = uu;
    }
    if (lane == 12) {                           // c = bv.wt + bo
        float cc = bo[g];
        #pragma unroll
        for (int t = 0; t < 9; ++t) cc += bv[g * 9 + t] * wt[t];
        wuc[bg * 16 + 9] = cc;
    }
}

// ---------------- K3: stream outputs (no LDS, no barriers) ----------------
__global__ void __launch_bounds__(512, 4)
k3_out(const float* __restrict__ x, const float* __restrict__ wuc,
       float* __restrict__ out)
{
    const int bg  = blockIdx.x;
    const int tid = threadIdx.x;
    const int ow  = tid & 63;
    const int wv  = tid >> 6;
    const int oh0 = wv * PPT;

    const float* __restrict__ xp = x + (size_t)bg * PLANE;
    const float* __restrict__ up = wuc + bg * 16;

    float ur[9];
    #pragma unroll
    for (int i = 0; i < 9; ++i) ur[i] = up[i];
    const float cc = up[9];

    const bool c2  = (ow < 63);
    const int  ih0 = oh0 * 2 - 1;
    float* __restrict__ op = out + (size_t)bg * PN;

    // sliding 3-row window; compiler hoists loads up to the 64-VGPR budget
    float a0, b0, a1, b1, a2, b2;
#define LOAD_PAIR(A, B, ihv)                                                   \
    {                                                                          \
        const int ih_ = (ihv);                                                 \
        A = 0.f; B = 0.f;                                                      \
        if ((unsigned)ih_ < (unsigned)IMG) {                                   \
            const float* __restrict__ rp_ = xp + ih_ * IMG + 2 * ow;           \
            A = rp_[0];                                                        \
            if (c2) B = rp_[1];                                                \
        }                                                                      \
    }
    LOAD_PAIR(a0, b0, ih0 + 0);
    LOAD_PAIR(a1, b1, ih0 + 1);
    LOAD_PAIR(a2, b2, ih0 + 2);
    #pragma unroll
    for (int k = 0; k < PPT; ++k) {
        float o = cc;
        o += dpp_wave_shr1(b0) * ur[0]; o += a0 * ur[1]; o += b0 * ur[2];
        o += dpp_wave_shr1(b1) * ur[3]; o += a1 * ur[4]; o += b1 * ur[5];
        o += dpp_wave_shr1(b2) * ur[6]; o += a2 * ur[7]; o += b2 * ur[8];
        op[(oh0 + k) * 64 + ow] = o;
        if (k < PPT - 1) {
            a0 = a2; b0 = b2;
            LOAD_PAIR(a1, b1, ih0 + 2 * k + 3);
            LOAD_PAIR(a2, b2, ih0 + 2 * k + 4);
        }
    }
#undef LOAD_PAIR
}

extern "C" void kernel_launch(void* const* d_in, const int* in_sizes, int n_in,
                              void* d_out, int out_size, void* d_ws, size_t ws_size,
                              hipStream_t stream) {
    (void)in_sizes; (void)n_in; (void)ws_size; (void)out_size;
    const float* x  = (const float*)d_in[0];
    const float* Wq = (const float*)d_in[1];
    const float* bq = (const float*)d_in[2];
    const float* Wk = (const float*)d_in[3];
    const float* bk = (const float*)d_in[4];
    const float* Wv = (const float*)d_in[5];
    const float* bv = (const float*)d_in[6];
    const float* Wo = (const float*)d_in[7];
    const float* bo = (const float*)d_in[8];
    float* out = (float*)d_out;
    float* wsp = (float*)d_ws;                  // [1024*64] partials
    float* wuc = wsp + WS_UC;                   // [1024*16] u+c

    hipLaunchKernelGGL(k1_gram, dim3(NB * 64), dim3(512), 0, stream, x, wsp);
    hipLaunchKernelGGL(k2_tiny, dim3(NB * 64), dim3(64), 0, stream,
                       wsp, wuc, Wq, bq, Wk, bk, Wv, bv, Wo, bo);
    hipLaunchKernelGGL(k3_out, dim3(NB * 64), dim3(512), 0, stream, x, wuc, out);
}